// Round 9
// baseline (156.688 us; speedup 1.0000x reference)
//
#include <hip/hip_runtime.h>

#define BSZ 8
#define SEQ 512
#define HID 768
#define N1 128
#define N2 24
#define HS 64
#define HEADS 12
#define INFV 10000.0f
#define NBLK 256

typedef __attribute__((ext_vector_type(8))) short s8b;     // 8 bf16 (4 VGPR)
typedef __attribute__((ext_vector_type(4))) float f32x4;   // MFMA acc

struct SharedA {
    unsigned short aF[96 * 16 * 8];   // 24 KB, XOR-swizzled slots
    float ps[16][64];                 // K-half-1 partials
    float xs[16][72];                 // x tile
    float kT[32][17];                 // kwT transpose staging
};
struct SharedB {
    float q_lds[8][HS];
    float bo[8][HEADS];
    int amm[8];
};
union SharedU { SharedA a; SharedB b; };

__device__ __forceinline__ unsigned short f2bf(float f) {
    union { float f; unsigned int u; } c; c.f = f;
    unsigned int u = c.u;
    u += 0x7FFFu + ((u >> 16) & 1u);   // RNE
    return (unsigned short)(u >> 16);
}

// Build bf16 B-fragment from W1 column cg, 8 consecutive k (stride N1 floats).
__device__ __forceinline__ s8b loadB(const float* __restrict__ wsrc) {
    union { s8b v; unsigned short u[8]; } r;
#pragma unroll
    for (int i = 0; i < 8; ++i) r.u[i] = f2bf(wsrc[i * N1]);
    return r.v;
}

// A-fragment slot (XOR-swizzled): chunk = global k/8, row = lr
#define ASLOT(chunk, r) (((chunk) * 16 + ((r) ^ ((chunk) & 7))) * 8)

// Phase A job: 16 rows x 64 cols of x = inp@W1+b1 (bf16 MFMA, K-split waves),
// epilogue RoPE -> qw + kwT, bias partial -> bP[ch].
__device__ __forceinline__ void phaseA(
    int job, int tid, SharedA& s,
    const float* __restrict__ inp, const float* __restrict__ W1,
    const float* __restrict__ b1, const float* __restrict__ W2,
    const float* __restrict__ b2,
    float* __restrict__ qw, float* __restrict__ kwT,
    float* __restrict__ bP0, float* __restrict__ bP1)
{
    const int rt = job >> 1;
    const int ch = job & 1;               // col half
    const int row0 = rt * 16;
    const int b = row0 >> 9;
    const int m0 = row0 & 511;

    {   // stage inp (fp32 -> bf16 swizzled fragment layout)
        const float4* src = (const float4*)(inp + (size_t)row0 * HID);
#pragma unroll
        for (int i = 0; i < 6; ++i) {
            int f4 = tid + i * 512;        // 0..3071
            int r = f4 / 192;              // row 0..15
            int c4 = f4 % 192;             // float4 idx in row; k = c4*4
            float4 v = src[f4];
            int chunk = c4 >> 1;
            int half = c4 & 1;
            ushort4 w;
            w.x = f2bf(v.x); w.y = f2bf(v.y); w.z = f2bf(v.z); w.w = f2bf(v.w);
            *(ushort4*)&s.aF[ASLOT(chunk, r) + half * 4] = w;
        }
    }
    __syncthreads();

    const int wv = tid >> 6;
    const int ln = tid & 63;
    const int lr = ln & 15;        // A row / B col within tile
    const int lg = ln >> 4;        // k-group
    const int w3 = wv & 3;         // col tile
    const int kh = wv >> 2;        // K half
    const int cg = ch * 64 + w3 * 16 + lr;   // global x-col

    const float* wbase = W1 + (size_t)(kh * 384 + lg * 8) * N1 + cg;

    f32x4 acc = {0.f, 0.f, 0.f, 0.f};
    s8b bA = loadB(wbase);
    s8b bB = loadB(wbase + 32 * N1);

#define AFRAG(kc) (*(const s8b*)&s.aF[ASLOT((kh * 12 + (kc)) * 4 + lg, lr)])
#pragma unroll
    for (int kc = 0; kc < 12; kc += 2) {
        acc = __builtin_amdgcn_mfma_f32_16x16x32_bf16(AFRAG(kc), bA, acc, 0, 0, 0);
        if (kc + 2 < 12) bA = loadB(wbase + (size_t)(kc + 2) * 32 * N1);
        acc = __builtin_amdgcn_mfma_f32_16x16x32_bf16(AFRAG(kc + 1), bB, acc, 0, 0, 0);
        if (kc + 3 < 12) bB = loadB(wbase + (size_t)(kc + 3) * 32 * N1);
    }
#undef AFRAG

    if (kh == 1) {   // upper-K partials -> LDS
#pragma unroll
        for (int g = 0; g < 4; ++g) s.ps[lg * 4 + g][w3 * 16 + lr] = acc[g];
    }
    __syncthreads();
    if (kh == 0) {   // merge + b1 -> xs
        float b1v = b1[cg];
#pragma unroll
        for (int g = 0; g < 4; ++g)
            s.xs[lg * 4 + g][w3 * 16 + lr] = acc[g] + s.ps[lg * 4 + g][w3 * 16 + lr] + b1v;
    }
    __syncthreads();

    // bias partial: bP[ch][(b,c,m)] = (x_half . W2[half,c] [+ b2 if ch==0]) * 0.5
    if (tid < 16 * N2) {
        int r = tid / N2, c = tid - r * N2;
        const float* w2p = W2 + (size_t)(ch * 64) * N2 + c;
        float dot = (ch == 0) ? b2[c] : 0.0f;
#pragma unroll 8
        for (int kl = 0; kl < 64; ++kl)
            dot = fmaf(s.xs[r][kl], w2p[kl * N2], dot);
        float* bP = ch ? bP1 : bP0;
        bP[(size_t)(b * N2 + c) * SEQ + m0 + r] = dot * 0.5f;
    }

    if (tid < 256) {   // RoPE: 16 rows x 16 local pairs (j = ch*16 + jj)
        const int r = tid >> 4, jj = tid & 15;
        const int j = ch * 16 + jj;
        const int m = m0 + r;
        const float C = 0.4152410118609203f;      // log2(10000)/32
        float invf = exp2f(-(float)j * C);        // 10000^(-j/32)
        float ang = (float)m * invf;
        float sv = __sinf(ang), cv = __cosf(ang);
        float4 xv = *(const float4*)&s.xs[r][4 * jj];
        float rq0 = xv.x * cv - xv.z * sv;        // q pair = x[4j], x[4j+2]
        float rq1 = xv.x * sv + xv.z * cv;
        float rk0 = xv.y * cv - xv.w * sv;        // k pair = x[4j+1], x[4j+3]
        float rk1 = xv.y * sv + xv.w * cv;
        *(float2*)(qw + (size_t)(b * SEQ + m) * HS + 2 * j) = make_float2(rq0, rq1);
        s.kT[2 * jj][r]     = rk0;
        s.kT[2 * jj + 1][r] = rk1;
    }
    __syncthreads();

    if (tid < 256) {   // kwT writeout: 32 local d-rows x 8 m-pairs
        int dl = tid >> 3, q = tid & 7;
        float2 v = *(const float2*)&s.kT[dl][2 * q];
        *(float2*)(kwT + (size_t)(b * HS + ch * 32 + dl) * SEQ + m0 + 2 * q) = v;
    }
}

// Phase B job: 8 m-rows x 512 n (1 n per thread) -> logits + mask.
__device__ __forceinline__ void phaseB(
    int job, int tid, SharedB& s,
    const float* __restrict__ qw, const float* __restrict__ kwT,
    const float* __restrict__ bP0, const float* __restrict__ bP1,
    const int* __restrict__ am, float* __restrict__ out)
{
    const int b = job >> 6;
    const int m0 = (job & 63) * 8;

    s.q_lds[tid >> 6][tid & 63] = qw[(size_t)(b * SEQ + m0) * HS + tid];
    if (tid < 96) {
        int r = tid / 12, h = tid - r * 12;
        size_t ix = (size_t)(b * N2 + 2 * h + 1) * SEQ + m0 + r;
        s.bo[r][h] = bP0[ix] + bP1[ix];
    }
    if (tid < 8) s.amm[tid] = am[b * SEQ + m0 + tid];
    __syncthreads();

    const int n = tid;
    float qk[8] = {0, 0, 0, 0, 0, 0, 0, 0};

#pragma unroll
    for (int dc = 0; dc < 2; ++dc) {
        float kn[32];
#pragma unroll
        for (int d = 0; d < 32; ++d)
            kn[d] = kwT[(size_t)(b * HS + dc * 32 + d) * SEQ + n];
#pragma unroll
        for (int r = 0; r < 8; ++r) {
#pragma unroll
            for (int d4 = 0; d4 < 8; ++d4) {
                float4 qv = *(const float4*)&s.q_lds[r][dc * 32 + d4 * 4];
                qk[r] = fmaf(qv.x, kn[d4 * 4 + 0], qk[r]);
                qk[r] = fmaf(qv.y, kn[d4 * 4 + 1], qk[r]);
                qk[r] = fmaf(qv.z, kn[d4 * 4 + 2], qk[r]);
                qk[r] = fmaf(qv.w, kn[d4 * 4 + 3], qk[r]);
            }
        }
    }

    const int amn = am[b * SEQ + n];
    float pen[8], mo[8];
#pragma unroll
    for (int r = 0; r < 8; ++r) {
        int m = m0 + r;
        float msk = (1.0f - (float)(amn * s.amm[r])) * INFV;
        pen[r] = msk + ((n < m) ? INFV : 0.0f);
        mo[r] = ((amn * s.amm[r] != 1) || (n < m)) ? 1.0f : 0.0f;
    }

    float be[HEADS];
#pragma unroll
    for (int h = 0; h < HEADS; ++h) {
        size_t ix = (size_t)(b * N2 + 2 * h) * SEQ + n;
        be[h] = bP0[ix] + bP1[ix];
    }

    const size_t obase = (size_t)b * HEADS * SEQ * SEQ + n;
#pragma unroll
    for (int h = 0; h < HEADS; ++h) {
#pragma unroll
        for (int r = 0; r < 8; ++r) {
            out[obase + ((size_t)h * SEQ + m0 + r) * SEQ] =
                fmaf(qk[r], 0.125f, be[h] + s.bo[r][h]) - pen[r];
        }
    }
    const size_t mbase = (size_t)BSZ * HEADS * SEQ * SEQ
                       + ((size_t)b * SEQ + m0) * SEQ + n;
#pragma unroll
    for (int r = 0; r < 8; ++r)
        out[mbase + (size_t)r * SEQ] = mo[r];
}

// Fused: 256 blocks x 512 thr; 2 A-jobs -> manual grid barrier -> 2 B-jobs.
// Co-residency by capacity: 256 blocks on 256 CUs, ~35 KB LDS (<=4 fit/CU),
// so every block is resident and the barrier cannot deadlock.
__global__ __launch_bounds__(512, 2) void fused_egp(
    const float* __restrict__ inp, const float* __restrict__ W1,
    const float* __restrict__ b1, const float* __restrict__ W2,
    const float* __restrict__ b2, const int* __restrict__ am,
    float* __restrict__ qw, float* __restrict__ kwT,
    float* __restrict__ bP0, float* __restrict__ bP1,
    unsigned int* __restrict__ ctr, float* __restrict__ out)
{
    __shared__ SharedU u;
    const int tid = threadIdx.x;
    const int bid = blockIdx.x;

#pragma unroll
    for (int j = 0; j < 2; ++j) {
        if (j) __syncthreads();
        phaseA(bid * 2 + j, tid, u.a, inp, W1, b1, W2, b2, qw, kwT, bP0, bP1);
    }

    // ---- single-use grid barrier (ctr zeroed by hipMemsetAsync each call) ----
    __syncthreads();
    __threadfence();                               // phase-A stores device-visible
    if (tid == 0)
        __hip_atomic_fetch_add(ctr, 1u, __ATOMIC_RELEASE, __HIP_MEMORY_SCOPE_AGENT);
    while (__hip_atomic_load(ctr, __ATOMIC_ACQUIRE, __HIP_MEMORY_SCOPE_AGENT) < NBLK)
        __builtin_amdgcn_s_sleep(8);
    __threadfence();                               // no stale cached reads
    __syncthreads();

#pragma unroll
    for (int j = 0; j < 2; ++j) {
        if (j) __syncthreads();
        phaseB(bid * 2 + j, tid, u.b, qw, kwT, bP0, bP1, am, out);
    }
}

extern "C" void kernel_launch(void* const* d_in, const int* in_sizes, int n_in,
                              void* d_out, int out_size, void* d_ws, size_t ws_size,
                              hipStream_t stream) {
    const float* inp = (const float*)d_in[0];
    const int*   am  = (const int*)d_in[1];
    const float* W1  = (const float*)d_in[2];
    const float* b1  = (const float*)d_in[3];
    const float* W2  = (const float*)d_in[4];
    const float* b2  = (const float*)d_in[5];

    float* ws    = (float*)d_ws;
    float* qw    = ws;                              // 262144 floats
    float* kwT   = ws + 262144;                     // 262144 floats
    float* bP0   = ws + 524288;                     //  98304 floats
    float* bP1   = ws + 622592;                     //  98304 floats
    unsigned int* ctr = (unsigned int*)(ws + 720896);

    float* out = (float*)d_out;

    hipMemsetAsync(ctr, 0, sizeof(unsigned int), stream);
    hipLaunchKernelGGL(fused_egp, dim3(NBLK), dim3(512), 0, stream,
                       inp, W1, b1, W2, b2, am, qw, kwT, bP0, bP1, ctr, out);
}

// Round 10
// 122.498 us; speedup vs baseline: 1.2791x; 1.2791x over previous
//
#include <hip/hip_runtime.h>

#define BSZ 8
#define SEQ 512
#define HID 768
#define N1 128
#define N2 24
#define HS 64
#define HEADS 12
#define INFV 10000.0f
#define NBLK 256

typedef __attribute__((ext_vector_type(8))) short s8b;     // 8 bf16 (4 VGPR)
typedef __attribute__((ext_vector_type(4))) float f32x4;   // MFMA acc

struct SharedA {
    unsigned short aF[96 * 16 * 8];   // 24 KB, XOR-swizzled slots
    float ps[16][64];                 // K-half-1 partials
    float xs[16][72];                 // x tile
    float kT[32][17];                 // kwT transpose staging
};
struct SharedB {
    float q_lds[8][HS];
    float bo[8][HEADS];
    int amm[8];
};
union SharedU { SharedA a; SharedB b; };

__device__ __forceinline__ unsigned short f2bf(float f) {
    union { float f; unsigned int u; } c; c.f = f;
    unsigned int u = c.u;
    u += 0x7FFFu + ((u >> 16) & 1u);   // RNE
    return (unsigned short)(u >> 16);
}

// Build bf16 B-fragment from W1 column cg, 8 consecutive k (stride N1 floats).
__device__ __forceinline__ s8b loadB(const float* __restrict__ wsrc) {
    union { s8b v; unsigned short u[8]; } r;
#pragma unroll
    for (int i = 0; i < 8; ++i) r.u[i] = f2bf(wsrc[i * N1]);
    return r.v;
}

// A-fragment slot (XOR-swizzled): chunk = global k/8, row = lr
#define ASLOT(chunk, r) (((chunk) * 16 + ((r) ^ ((chunk) & 7))) * 8)

// Phase A job: 16 rows x 64 cols of x = inp@W1+b1 (bf16 MFMA, K-split waves),
// epilogue RoPE -> qw + kwT, bias partial -> bP[ch].
__device__ __forceinline__ void phaseA(
    int job, int tid, SharedA& s,
    const float* __restrict__ inp, const float* __restrict__ W1,
    const float* __restrict__ b1, const float* __restrict__ W2,
    const float* __restrict__ b2,
    float* __restrict__ qw, float* __restrict__ kwT,
    float* __restrict__ bP0, float* __restrict__ bP1)
{
    const int rt = job >> 1;
    const int ch = job & 1;               // col half
    const int row0 = rt * 16;
    const int b = row0 >> 9;
    const int m0 = row0 & 511;

    {   // stage inp (fp32 -> bf16 swizzled fragment layout)
        const float4* src = (const float4*)(inp + (size_t)row0 * HID);
#pragma unroll
        for (int i = 0; i < 6; ++i) {
            int f4 = tid + i * 512;        // 0..3071
            int r = f4 / 192;              // row 0..15
            int c4 = f4 % 192;             // float4 idx in row; k = c4*4
            float4 v = src[f4];
            int chunk = c4 >> 1;
            int half = c4 & 1;
            ushort4 w;
            w.x = f2bf(v.x); w.y = f2bf(v.y); w.z = f2bf(v.z); w.w = f2bf(v.w);
            *(ushort4*)&s.aF[ASLOT(chunk, r) + half * 4] = w;
        }
    }
    __syncthreads();

    const int wv = tid >> 6;
    const int ln = tid & 63;
    const int lr = ln & 15;        // A row / B col within tile
    const int lg = ln >> 4;        // k-group
    const int w3 = wv & 3;         // col tile
    const int kh = wv >> 2;        // K half
    const int cg = ch * 64 + w3 * 16 + lr;   // global x-col

    const float* wbase = W1 + (size_t)(kh * 384 + lg * 8) * N1 + cg;

    f32x4 acc = {0.f, 0.f, 0.f, 0.f};
    s8b bA = loadB(wbase);
    s8b bB = loadB(wbase + 32 * N1);

#define AFRAG(kc) (*(const s8b*)&s.aF[ASLOT((kh * 12 + (kc)) * 4 + lg, lr)])
#pragma unroll
    for (int kc = 0; kc < 12; kc += 2) {
        acc = __builtin_amdgcn_mfma_f32_16x16x32_bf16(AFRAG(kc), bA, acc, 0, 0, 0);
        if (kc + 2 < 12) bA = loadB(wbase + (size_t)(kc + 2) * 32 * N1);
        acc = __builtin_amdgcn_mfma_f32_16x16x32_bf16(AFRAG(kc + 1), bB, acc, 0, 0, 0);
        if (kc + 3 < 12) bB = loadB(wbase + (size_t)(kc + 3) * 32 * N1);
    }
#undef AFRAG

    if (kh == 1) {   // upper-K partials -> LDS
#pragma unroll
        for (int g = 0; g < 4; ++g) s.ps[lg * 4 + g][w3 * 16 + lr] = acc[g];
    }
    __syncthreads();
    if (kh == 0) {   // merge + b1 -> xs
        float b1v = b1[cg];
#pragma unroll
        for (int g = 0; g < 4; ++g)
            s.xs[lg * 4 + g][w3 * 16 + lr] = acc[g] + s.ps[lg * 4 + g][w3 * 16 + lr] + b1v;
    }
    __syncthreads();

    // bias partial: bP[ch][(b,c,m)] = (x_half . W2[half,c] [+ b2 if ch==0]) * 0.5
    if (tid < 16 * N2) {
        int r = tid / N2, c = tid - r * N2;
        const float* w2p = W2 + (size_t)(ch * 64) * N2 + c;
        float dot = (ch == 0) ? b2[c] : 0.0f;
#pragma unroll 8
        for (int kl = 0; kl < 64; ++kl)
            dot = fmaf(s.xs[r][kl], w2p[kl * N2], dot);
        float* bP = ch ? bP1 : bP0;
        bP[(size_t)(b * N2 + c) * SEQ + m0 + r] = dot * 0.5f;
    }

    if (tid < 256) {   // RoPE: 16 rows x 16 local pairs (j = ch*16 + jj)
        const int r = tid >> 4, jj = tid & 15;
        const int j = ch * 16 + jj;
        const int m = m0 + r;
        const float C = 0.4152410118609203f;      // log2(10000)/32
        float invf = exp2f(-(float)j * C);        // 10000^(-j/32)
        float ang = (float)m * invf;
        float sv = __sinf(ang), cv = __cosf(ang);
        float4 xv = *(const float4*)&s.xs[r][4 * jj];
        float rq0 = xv.x * cv - xv.z * sv;        // q pair = x[4j], x[4j+2]
        float rq1 = xv.x * sv + xv.z * cv;
        float rk0 = xv.y * cv - xv.w * sv;        // k pair = x[4j+1], x[4j+3]
        float rk1 = xv.y * sv + xv.w * cv;
        *(float2*)(qw + (size_t)(b * SEQ + m) * HS + 2 * j) = make_float2(rq0, rq1);
        s.kT[2 * jj][r]     = rk0;
        s.kT[2 * jj + 1][r] = rk1;
    }
    __syncthreads();

    if (tid < 256) {   // kwT writeout: 32 local d-rows x 8 m-pairs
        int dl = tid >> 3, q = tid & 7;
        float2 v = *(const float2*)&s.kT[dl][2 * q];
        *(float2*)(kwT + (size_t)(b * HS + ch * 32 + dl) * SEQ + m0 + 2 * q) = v;
    }
}

// Phase B job: 8 m-rows x 512 n (1 n per thread) -> logits + mask.
__device__ __forceinline__ void phaseB(
    int job, int tid, SharedB& s,
    const float* __restrict__ qw, const float* __restrict__ kwT,
    const float* __restrict__ bP0, const float* __restrict__ bP1,
    const int* __restrict__ am, float* __restrict__ out)
{
    const int b = job >> 6;
    const int m0 = (job & 63) * 8;

    s.q_lds[tid >> 6][tid & 63] = qw[(size_t)(b * SEQ + m0) * HS + tid];
    if (tid < 96) {
        int r = tid / 12, h = tid - r * 12;
        size_t ix = (size_t)(b * N2 + 2 * h + 1) * SEQ + m0 + r;
        s.bo[r][h] = bP0[ix] + bP1[ix];
    }
    if (tid < 8) s.amm[tid] = am[b * SEQ + m0 + tid];
    __syncthreads();

    const int n = tid;
    float qk[8] = {0, 0, 0, 0, 0, 0, 0, 0};

#pragma unroll
    for (int dc = 0; dc < 2; ++dc) {
        float kn[32];
#pragma unroll
        for (int d = 0; d < 32; ++d)
            kn[d] = kwT[(size_t)(b * HS + dc * 32 + d) * SEQ + n];
#pragma unroll
        for (int r = 0; r < 8; ++r) {
#pragma unroll
            for (int d4 = 0; d4 < 8; ++d4) {
                float4 qv = *(const float4*)&s.q_lds[r][dc * 32 + d4 * 4];
                qk[r] = fmaf(qv.x, kn[d4 * 4 + 0], qk[r]);
                qk[r] = fmaf(qv.y, kn[d4 * 4 + 1], qk[r]);
                qk[r] = fmaf(qv.z, kn[d4 * 4 + 2], qk[r]);
                qk[r] = fmaf(qv.w, kn[d4 * 4 + 3], qk[r]);
            }
        }
    }

    const int amn = am[b * SEQ + n];
    float pen[8], mo[8];
#pragma unroll
    for (int r = 0; r < 8; ++r) {
        int m = m0 + r;
        float msk = (1.0f - (float)(amn * s.amm[r])) * INFV;
        pen[r] = msk + ((n < m) ? INFV : 0.0f);
        mo[r] = ((amn * s.amm[r] != 1) || (n < m)) ? 1.0f : 0.0f;
    }

    float be[HEADS];
#pragma unroll
    for (int h = 0; h < HEADS; ++h) {
        size_t ix = (size_t)(b * N2 + 2 * h) * SEQ + n;
        be[h] = bP0[ix] + bP1[ix];
    }

    const size_t obase = (size_t)b * HEADS * SEQ * SEQ + n;
#pragma unroll
    for (int h = 0; h < HEADS; ++h) {
#pragma unroll
        for (int r = 0; r < 8; ++r) {
            out[obase + ((size_t)h * SEQ + m0 + r) * SEQ] =
                fmaf(qk[r], 0.125f, be[h] + s.bo[r][h]) - pen[r];
        }
    }
    const size_t mbase = (size_t)BSZ * HEADS * SEQ * SEQ
                       + ((size_t)b * SEQ + m0) * SEQ + n;
#pragma unroll
    for (int r = 0; r < 8; ++r)
        out[mbase + (size_t)r * SEQ] = mo[r];
}

// Fused: 256 blocks x 512 thr; 2 A-jobs -> manual grid barrier -> 2 B-jobs.
// Barrier: ONLY tid==0 per block adds + polls (256 pollers, s_sleep-paced);
// remaining threads park at __syncthreads. Avoids the round-9 livelock where
// 131K spinning threads starved the release adds at the coherence point.
__global__ __launch_bounds__(512, 2) void fused_egp(
    const float* __restrict__ inp, const float* __restrict__ W1,
    const float* __restrict__ b1, const float* __restrict__ W2,
    const float* __restrict__ b2, const int* __restrict__ am,
    float* __restrict__ qw, float* __restrict__ kwT,
    float* __restrict__ bP0, float* __restrict__ bP1,
    unsigned int* __restrict__ ctr, float* __restrict__ out)
{
    __shared__ SharedU u;
    const int tid = threadIdx.x;
    const int bid = blockIdx.x;

#pragma unroll
    for (int j = 0; j < 2; ++j) {
        if (j) __syncthreads();
        phaseA(bid * 2 + j, tid, u.a, inp, W1, b1, W2, b2, qw, kwT, bP0, bP1);
    }

    // ---- single-use grid barrier (ctr zeroed by hipMemsetAsync each call) ----
    __syncthreads();
    __threadfence();                               // phase-A stores device-visible
    if (tid == 0) {
        __hip_atomic_fetch_add(ctr, 1u, __ATOMIC_RELEASE, __HIP_MEMORY_SCOPE_AGENT);
        while (__hip_atomic_load(ctr, __ATOMIC_ACQUIRE, __HIP_MEMORY_SCOPE_AGENT) < NBLK)
            __builtin_amdgcn_s_sleep(32);          // ~0.85 us between polls
    }
    __syncthreads();
    __threadfence();                               // no stale cached reads

#pragma unroll
    for (int j = 0; j < 2; ++j) {
        if (j) __syncthreads();
        phaseB(bid * 2 + j, tid, u.b, qw, kwT, bP0, bP1, am, out);
    }
}

extern "C" void kernel_launch(void* const* d_in, const int* in_sizes, int n_in,
                              void* d_out, int out_size, void* d_ws, size_t ws_size,
                              hipStream_t stream) {
    const float* inp = (const float*)d_in[0];
    const int*   am  = (const int*)d_in[1];
    const float* W1  = (const float*)d_in[2];
    const float* b1  = (const float*)d_in[3];
    const float* W2  = (const float*)d_in[4];
    const float* b2  = (const float*)d_in[5];

    float* ws    = (float*)d_ws;
    float* qw    = ws;                              // 262144 floats
    float* kwT   = ws + 262144;                     // 262144 floats
    float* bP0   = ws + 524288;                     //  98304 floats
    float* bP1   = ws + 622592;                     //  98304 floats
    unsigned int* ctr = (unsigned int*)(ws + 720896);

    float* out = (float*)d_out;

    hipMemsetAsync(ctr, 0, sizeof(unsigned int), stream);
    hipLaunchKernelGGL(fused_egp, dim3(NBLK), dim3(512), 0, stream,
                       inp, W1, b1, W2, b2, am, qw, kwT, bP0, bP1, ctr, out);
}

// Round 11
// 40.618 us; speedup vs baseline: 3.8576x; 3.0158x over previous
//
#include <hip/hip_runtime.h>

#define BSZ 8
#define SEQ 512
#define HID 768
#define N1 128
#define N2 24
#define HS 64
#define HEADS 12
#define INFV 10000.0f

typedef __attribute__((ext_vector_type(8))) short s8b;     // 8 bf16 (4 VGPR)
typedef __attribute__((ext_vector_type(4))) float f32x4;   // MFMA acc

__device__ __forceinline__ unsigned short f2bf(float f) {
    union { float f; unsigned int u; } c; c.f = f;
    unsigned int u = c.u;
    u += 0x7FFFu + ((u >> 16) & 1u);   // RNE
    return (unsigned short)(u >> 16);
}

// Build bf16 B-fragment from W1 column cg, 8 consecutive k (stride N1 floats).
__device__ __forceinline__ s8b loadB(const float* __restrict__ wsrc) {
    union { s8b v; unsigned short u[8]; } r;
#pragma unroll
    for (int i = 0; i < 8; ++i) r.u[i] = f2bf(wsrc[i * N1]);
    return r.v;
}

// A-fragment slot (XOR-swizzled): chunk = global k/8, row = lr
#define ASLOT(chunk, r) (((chunk) * 16 + ((r) ^ ((chunk) & 7))) * 8)

// k1: 512 blocks x 512 thr. Block = 16 rows x 64 cols (col-half ch = bid&1).
// 8 waves = 4 col-tiles x 2 K-halves; bf16 MFMA; A staged in swizzled LDS,
// B converted in-register from W1. Epilogue: native-sincos RoPE -> qw + kwT,
// bias partial (x_half @ W2) -> bP[ch].   [R7-proven version, unchanged]
__global__ __launch_bounds__(512, 4) void k1_proj(
    const float* __restrict__ inp, const float* __restrict__ W1,
    const float* __restrict__ b1, const float* __restrict__ W2,
    const float* __restrict__ b2,
    float* __restrict__ qw, float* __restrict__ kwT,
    float* __restrict__ bP0, float* __restrict__ bP1)
{
    __shared__ unsigned short aF[96 * 16 * 8];   // 24 KB, XOR-swizzled slots
    __shared__ float ps[16][64];                 // K-half-1 partials
    __shared__ float xs[16][72];                 // x tile
    __shared__ float kT[32][17];                 // kwT transpose staging

    const int tid = threadIdx.x;
    const int rt = blockIdx.x >> 1;
    const int ch = blockIdx.x & 1;               // col half
    const int row0 = rt * 16;
    const int b = row0 >> 9;
    const int m0 = row0 & 511;

    {   // stage inp (fp32 -> bf16 swizzled fragment layout)
        const float4* src = (const float4*)(inp + (size_t)row0 * HID);
#pragma unroll
        for (int i = 0; i < 6; ++i) {
            int f4 = tid + i * 512;        // 0..3071
            int r = f4 / 192;              // row 0..15
            int c4 = f4 % 192;             // float4 idx in row; k = c4*4
            float4 v = src[f4];
            int chunk = c4 >> 1;
            int half = c4 & 1;
            ushort4 w;
            w.x = f2bf(v.x); w.y = f2bf(v.y); w.z = f2bf(v.z); w.w = f2bf(v.w);
            *(ushort4*)&aF[ASLOT(chunk, r) + half * 4] = w;
        }
    }
    __syncthreads();

    const int wv = tid >> 6;
    const int ln = tid & 63;
    const int lr = ln & 15;        // A row / B col within tile
    const int lg = ln >> 4;        // k-group
    const int w3 = wv & 3;         // col tile
    const int kh = wv >> 2;        // K half
    const int cg = ch * 64 + w3 * 16 + lr;   // global x-col

    const float* wbase = W1 + (size_t)(kh * 384 + lg * 8) * N1 + cg;

    f32x4 acc = {0.f, 0.f, 0.f, 0.f};
    s8b bA = loadB(wbase);
    s8b bB = loadB(wbase + 32 * N1);

#define AFRAG(kc) (*(const s8b*)&aF[ASLOT((kh * 12 + (kc)) * 4 + lg, lr)])
#pragma unroll
    for (int kc = 0; kc < 12; kc += 2) {
        acc = __builtin_amdgcn_mfma_f32_16x16x32_bf16(AFRAG(kc), bA, acc, 0, 0, 0);
        if (kc + 2 < 12) bA = loadB(wbase + (size_t)(kc + 2) * 32 * N1);
        acc = __builtin_amdgcn_mfma_f32_16x16x32_bf16(AFRAG(kc + 1), bB, acc, 0, 0, 0);
        if (kc + 3 < 12) bB = loadB(wbase + (size_t)(kc + 3) * 32 * N1);
    }
#undef AFRAG

    if (kh == 1) {   // upper-K partials -> LDS
#pragma unroll
        for (int g = 0; g < 4; ++g) ps[lg * 4 + g][w3 * 16 + lr] = acc[g];
    }
    __syncthreads();
    if (kh == 0) {   // merge + b1 -> xs
        float b1v = b1[cg];
#pragma unroll
        for (int g = 0; g < 4; ++g)
            xs[lg * 4 + g][w3 * 16 + lr] = acc[g] + ps[lg * 4 + g][w3 * 16 + lr] + b1v;
    }
    __syncthreads();

    // bias partial: bP[ch][(b,c,m)] = (x_half . W2[half,c] [+ b2 if ch==0]) * 0.5
    if (tid < 16 * N2) {
        int r = tid / N2, c = tid - r * N2;
        const float* w2p = W2 + (size_t)(ch * 64) * N2 + c;
        float dot = (ch == 0) ? b2[c] : 0.0f;
#pragma unroll 8
        for (int kl = 0; kl < 64; ++kl)
            dot = fmaf(xs[r][kl], w2p[kl * N2], dot);
        float* bP = ch ? bP1 : bP0;
        bP[(size_t)(b * N2 + c) * SEQ + m0 + r] = dot * 0.5f;
    }

    if (tid < 256) {   // RoPE: 16 rows x 16 local pairs (j = ch*16 + jj)
        const int r = tid >> 4, jj = tid & 15;
        const int j = ch * 16 + jj;
        const int m = m0 + r;
        const float C = 0.4152410118609203f;      // log2(10000)/32
        float invf = exp2f(-(float)j * C);        // 10000^(-j/32)
        float ang = (float)m * invf;
        float sv = __sinf(ang), cv = __cosf(ang);
        float4 xv = *(const float4*)&xs[r][4 * jj];
        float rq0 = xv.x * cv - xv.z * sv;        // q pair = x[4j], x[4j+2]
        float rq1 = xv.x * sv + xv.z * cv;
        float rk0 = xv.y * cv - xv.w * sv;        // k pair = x[4j+1], x[4j+3]
        float rk1 = xv.y * sv + xv.w * cv;
        *(float2*)(qw + (size_t)(b * SEQ + m) * HS + 2 * j) = make_float2(rq0, rq1);
        kT[2 * jj][r]     = rk0;
        kT[2 * jj + 1][r] = rk1;
    }
    __syncthreads();

    if (tid < 256) {   // kwT writeout: 32 local d-rows x 8 m-pairs
        int dl = tid >> 3, q = tid & 7;
        float2 v = *(const float2*)&kT[dl][2 * q];
        *(float2*)(kwT + (size_t)(b * HS + ch * 32 + dl) * SEQ + m0 + 2 * q) = v;
    }
}

// k2: 512 blocks = (b, 8 m-rows); 256 thr = 2 row-groups x 128 n-quads.
// Each thread: 4 rows x 4 consecutive n -> all stores are float4 (1 KB/wave).
__global__ __launch_bounds__(256) void k2_out(
    const float* __restrict__ qw, const float* __restrict__ kwT,
    const float* __restrict__ bP0, const float* __restrict__ bP1,
    const int* __restrict__ am, float* __restrict__ out)
{
    __shared__ float q_lds[8][HS];
    __shared__ float bo[8][HEADS];
    __shared__ int amm[8];

    const int tid = threadIdx.x;
    const int b = blockIdx.x >> 6;
    const int m0 = (blockIdx.x & 63) * 8;

#pragma unroll
    for (int i = 0; i < 2; ++i) {
        int idx = tid + i * 256;
        q_lds[idx >> 6][idx & 63] = qw[(size_t)(b * SEQ + m0) * HS + idx];
    }
    if (tid < 96) {
        int r = tid / 12, h = tid - r * 12;
        size_t ix = (size_t)(b * N2 + 2 * h + 1) * SEQ + m0 + r;
        bo[r][h] = bP0[ix] + bP1[ix];
    }
    if (tid < 8) amm[tid] = am[b * SEQ + m0 + tid];
    __syncthreads();

    const int g = tid >> 7;            // row group: rows m0 + g*4 .. +3
    const int n0 = (tid & 127) * 4;    // 4 consecutive n

    float4 qk[4] = {{0,0,0,0},{0,0,0,0},{0,0,0,0},{0,0,0,0}};

#pragma unroll
    for (int d0 = 0; d0 < HS; d0 += 8) {
        float4 kn[8];
#pragma unroll
        for (int dd = 0; dd < 8; ++dd)
            kn[dd] = *(const float4*)&kwT[(size_t)(b * HS + d0 + dd) * SEQ + n0];
#pragma unroll
        for (int r = 0; r < 4; ++r) {
            float4 qa = *(const float4*)&q_lds[g * 4 + r][d0];       // wave-uniform
            float4 qb = *(const float4*)&q_lds[g * 4 + r][d0 + 4];
#pragma unroll
            for (int c = 0; c < 4; ++c) {
                float* k0 = (float*)&kn[0];
                // component-wise fmaf over the 4 n's
            }
            qk[r].x = fmaf(qa.x, kn[0].x, qk[r].x); qk[r].y = fmaf(qa.x, kn[0].y, qk[r].y);
            qk[r].z = fmaf(qa.x, kn[0].z, qk[r].z); qk[r].w = fmaf(qa.x, kn[0].w, qk[r].w);
            qk[r].x = fmaf(qa.y, kn[1].x, qk[r].x); qk[r].y = fmaf(qa.y, kn[1].y, qk[r].y);
            qk[r].z = fmaf(qa.y, kn[1].z, qk[r].z); qk[r].w = fmaf(qa.y, kn[1].w, qk[r].w);
            qk[r].x = fmaf(qa.z, kn[2].x, qk[r].x); qk[r].y = fmaf(qa.z, kn[2].y, qk[r].y);
            qk[r].z = fmaf(qa.z, kn[2].z, qk[r].z); qk[r].w = fmaf(qa.z, kn[2].w, qk[r].w);
            qk[r].x = fmaf(qa.w, kn[3].x, qk[r].x); qk[r].y = fmaf(qa.w, kn[3].y, qk[r].y);
            qk[r].z = fmaf(qa.w, kn[3].z, qk[r].z); qk[r].w = fmaf(qa.w, kn[3].w, qk[r].w);
            qk[r].x = fmaf(qb.x, kn[4].x, qk[r].x); qk[r].y = fmaf(qb.x, kn[4].y, qk[r].y);
            qk[r].z = fmaf(qb.x, kn[4].z, qk[r].z); qk[r].w = fmaf(qb.x, kn[4].w, qk[r].w);
            qk[r].x = fmaf(qb.y, kn[5].x, qk[r].x); qk[r].y = fmaf(qb.y, kn[5].y, qk[r].y);
            qk[r].z = fmaf(qb.y, kn[5].z, qk[r].z); qk[r].w = fmaf(qb.y, kn[5].w, qk[r].w);
            qk[r].x = fmaf(qb.z, kn[6].x, qk[r].x); qk[r].y = fmaf(qb.z, kn[6].y, qk[r].y);
            qk[r].z = fmaf(qb.z, kn[6].z, qk[r].z); qk[r].w = fmaf(qb.z, kn[6].w, qk[r].w);
            qk[r].x = fmaf(qb.w, kn[7].x, qk[r].x); qk[r].y = fmaf(qb.w, kn[7].y, qk[r].y);
            qk[r].z = fmaf(qb.w, kn[7].z, qk[r].z); qk[r].w = fmaf(qb.w, kn[7].w, qk[r].w);
        }
    }

    int4 amn = *(const int4*)&am[b * SEQ + n0];
    float4 pen[4], mo[4];
#pragma unroll
    for (int r = 0; r < 4; ++r) {
        int m = m0 + g * 4 + r;
        int a = amm[g * 4 + r];
        pen[r].x = (1.0f - (float)(amn.x * a)) * INFV + ((n0 + 0 < m) ? INFV : 0.0f);
        pen[r].y = (1.0f - (float)(amn.y * a)) * INFV + ((n0 + 1 < m) ? INFV : 0.0f);
        pen[r].z = (1.0f - (float)(amn.z * a)) * INFV + ((n0 + 2 < m) ? INFV : 0.0f);
        pen[r].w = (1.0f - (float)(amn.w * a)) * INFV + ((n0 + 3 < m) ? INFV : 0.0f);
        mo[r].x = ((amn.x * a != 1) || (n0 + 0 < m)) ? 1.0f : 0.0f;
        mo[r].y = ((amn.y * a != 1) || (n0 + 1 < m)) ? 1.0f : 0.0f;
        mo[r].z = ((amn.z * a != 1) || (n0 + 2 < m)) ? 1.0f : 0.0f;
        mo[r].w = ((amn.w * a != 1) || (n0 + 3 < m)) ? 1.0f : 0.0f;
    }

    const size_t obase = (size_t)b * HEADS * SEQ * SEQ + n0;
#pragma unroll
    for (int h = 0; h < HEADS; ++h) {
        size_t ix = (size_t)(b * N2 + 2 * h) * SEQ + n0;
        float4 e0 = *(const float4*)&bP0[ix];
        float4 e1 = *(const float4*)&bP1[ix];
        float4 be = {e0.x + e1.x, e0.y + e1.y, e0.z + e1.z, e0.w + e1.w};
#pragma unroll
        for (int r = 0; r < 4; ++r) {
            float bos = bo[g * 4 + r][h];
            float4 v;
            v.x = fmaf(qk[r].x, 0.125f, be.x + bos) - pen[r].x;
            v.y = fmaf(qk[r].y, 0.125f, be.y + bos) - pen[r].y;
            v.z = fmaf(qk[r].z, 0.125f, be.z + bos) - pen[r].z;
            v.w = fmaf(qk[r].w, 0.125f, be.w + bos) - pen[r].w;
            *(float4*)&out[obase + ((size_t)h * SEQ + m0 + g * 4 + r) * SEQ] = v;
        }
    }
    const size_t mbase = (size_t)BSZ * HEADS * SEQ * SEQ
                       + ((size_t)b * SEQ + m0 + g * 4) * SEQ + n0;
#pragma unroll
    for (int r = 0; r < 4; ++r)
        *(float4*)&out[mbase + (size_t)r * SEQ] = mo[r];
}

extern "C" void kernel_launch(void* const* d_in, const int* in_sizes, int n_in,
                              void* d_out, int out_size, void* d_ws, size_t ws_size,
                              hipStream_t stream) {
    const float* inp = (const float*)d_in[0];
    const int*   am  = (const int*)d_in[1];
    const float* W1  = (const float*)d_in[2];
    const float* b1  = (const float*)d_in[3];
    const float* W2  = (const float*)d_in[4];
    const float* b2  = (const float*)d_in[5];

    float* ws    = (float*)d_ws;
    float* qw    = ws;                              // 262144 floats
    float* kwT   = ws + 262144;                     // 262144 floats
    float* bP0   = ws + 524288;                     //  98304 floats
    float* bP1   = ws + 622592;                     //  98304 floats

    float* out = (float*)d_out;

    hipLaunchKernelGGL(k1_proj, dim3(512), dim3(512), 0, stream,
                       inp, W1, b1, W2, b2, qw, kwT, bP0, bP1);
    hipLaunchKernelGGL(k2_out, dim3(512), dim3(256), 0, stream,
                       qw, kwT, bP0, bP1, am, out);
}